// Round 3
// baseline (246.793 us; speedup 1.0000x reference)
//
#include <hip/hip_runtime.h>
#include <stdint.h>

#define QD 512   // query_dim
#define KD 256   // key_dim
#define NBATCH 2048
#define NK 512   // n_keys

// ---------------------------------------------------------------------------
// Kernel 1: TQ[b][k] = sum_q Q[b][q] * W[k][q] + bias[k]      (B=2048, KD=256)
// 512 blocks x 256 threads; 4 batch rows per block staged in LDS; thread t
// owns output column t and streams W[t][:] from L2 (W is 512 KB, L2-resident).
// ---------------------------------------------------------------------------
__global__ __launch_bounds__(256) void tq_gemm(const float* __restrict__ Q,
                                               const float* __restrict__ W,
                                               const float* __restrict__ bias,
                                               float* __restrict__ TQ) {
    __shared__ float qs[4][QD];
    const int b0 = blockIdx.x * 4;

    const float4* Qv = (const float4*)(Q + (size_t)b0 * QD);
    float4* qsv = (float4*)&qs[0][0];
    qsv[threadIdx.x]       = Qv[threadIdx.x];
    qsv[threadIdx.x + 256] = Qv[threadIdx.x + 256];
    __syncthreads();

    const int k = threadIdx.x;
    const float4* Wv = (const float4*)(W + (size_t)k * QD);

    float a0 = 0.f, a1 = 0.f, a2 = 0.f, a3 = 0.f;
#pragma unroll 4
    for (int kk = 0; kk < QD / 4; ++kk) {
        float4 w4 = Wv[kk];
        float4 q0 = *(const float4*)&qs[0][kk * 4];  // same-addr broadcast: free
        float4 q1 = *(const float4*)&qs[1][kk * 4];
        float4 q2 = *(const float4*)&qs[2][kk * 4];
        float4 q3 = *(const float4*)&qs[3][kk * 4];
        a0 += w4.x * q0.x + w4.y * q0.y + w4.z * q0.z + w4.w * q0.w;
        a1 += w4.x * q1.x + w4.y * q1.y + w4.z * q1.z + w4.w * q1.w;
        a2 += w4.x * q2.x + w4.y * q2.y + w4.z * q2.z + w4.w * q2.w;
        a3 += w4.x * q3.x + w4.y * q3.y + w4.z * q3.z + w4.w * q3.w;
    }
    const float bb = bias[k];
    TQ[(size_t)(b0 + 0) * KD + k] = a0 + bb;
    TQ[(size_t)(b0 + 1) * KD + k] = a1 + bb;
    TQ[(size_t)(b0 + 2) * KD + k] = a2 + bb;
    TQ[(size_t)(b0 + 3) * KD + k] = a3 + bb;
}

// ---------------------------------------------------------------------------
// Kernel 2: fused  alpha = keys . tq  -> mask -> online softmax -> PV
// One block (256 thr = 4 waves) per batch; wave owns 128 key rows; one row =
// 64 lanes x float4 = one coalesced 1 KB load. keys read EXACTLY ONCE (1 GiB).
// Mask is staged ONCE per block into an LDS additive bias {0, -inf} — the
// main loop issues NO global loads except key rows (keeps vmcnt pipeline
// pure). Mask dtype (int32 vs byte bool) detected per block from its own
// slice: any 32-bit word > 1 => byte layout (P[miss] ~ 2^-1536).
// ---------------------------------------------------------------------------
__global__ __launch_bounds__(256) void attn_fused(const float* __restrict__ keys,
                                                  const void* __restrict__ maskp,
                                                  const float* __restrict__ TQ,
                                                  float* __restrict__ out_att,
                                                  float* __restrict__ out_alpha) {
    const int b    = blockIdx.x;
    const int t    = threadIdx.x;
    const int wave = t >> 6;
    const int lane = t & 63;

    __shared__ float s_bias[NK];         // 0 or -inf
    __shared__ float s_alpha[NK];        // raw (masked) logits
    __shared__ float s_acc[4][KD];       // per-wave PV partials
    __shared__ float s_m[4], s_l[4];
    __shared__ int   s_flag[4];

    // ---- Phase 0: mask dtype probe + bias staging (once per block) ----
    const uint32_t* mw32 = (const uint32_t*)maskp + (size_t)b * NK;   // int32 view
    const uint32_t* mw8  = (const uint32_t*)((const uint8_t*)maskp + (size_t)b * NK);
    uint2 wv = ((const uint2*)mw32)[t];               // words 2t, 2t+1 of my slice
    const bool big = (wv.x > 1u) | (wv.y > 1u);
    const unsigned long long bal = __ballot(big);
    if (lane == 0) s_flag[wave] = (bal != 0ull);
    __syncthreads();
    const int bytemask = s_flag[0] | s_flag[1] | s_flag[2] | s_flag[3];
    if (bytemask) {
        if (t < NK / 4) {                             // 512 bytes = 128 words
            uint32_t w = mw8[t];
            s_bias[4 * t + 0] = (w & 0x000000FFu) ? -INFINITY : 0.f;
            s_bias[4 * t + 1] = (w & 0x0000FF00u) ? -INFINITY : 0.f;
            s_bias[4 * t + 2] = (w & 0x00FF0000u) ? -INFINITY : 0.f;
            s_bias[4 * t + 3] = (w & 0xFF000000u) ? -INFINITY : 0.f;
        }
    } else {
        s_bias[2 * t + 0] = wv.x ? -INFINITY : 0.f;
        s_bias[2 * t + 1] = wv.y ? -INFINITY : 0.f;
    }
    __syncthreads();

    // ---- Main loop ----
    const float4 tq4 = *(const float4*)(TQ + (size_t)b * KD + lane * 4);
    const float* kb  = keys + (size_t)b * NK * KD;

    float m = -1e30f, l = 0.f;
    float ax = 0.f, ay = 0.f, az = 0.f, aw = 0.f;

    const int n0 = wave * (NK / 4);      // this wave's 128 rows

    for (int i = 0; i < NK / 4; i += 8) {
        float4 k4[8];                    // 8 KB/wave in flight
#pragma unroll
        for (int r = 0; r < 8; ++r)
            k4[r] = *(const float4*)(kb + (size_t)(n0 + i + r) * KD + lane * 4);

#pragma unroll
        for (int r = 0; r < 8; ++r) {
            const int n = n0 + i + r;
            float d = k4[r].x * tq4.x + k4[r].y * tq4.y +
                      k4[r].z * tq4.z + k4[r].w * tq4.w;
#pragma unroll
            for (int off = 32; off > 0; off >>= 1)
                d += __shfl_xor(d, off, 64);

            const float aval = d + s_bias[n];         // -inf if masked
            if (lane == 0) s_alpha[n] = aval;

            // aval is wave-uniform -> branch is s_branch, no divergence.
            if (aval > m) {                            // rare (~ln(512) times)
                const float sc = __expf(m - aval);
                l *= sc; ax *= sc; ay *= sc; az *= sc; aw *= sc;
                m = aval;
            }
            const float w = __expf(aval - m);          // 0 for masked rows
            l += w;
            ax += w * k4[r].x; ay += w * k4[r].y;
            az += w * k4[r].z; aw += w * k4[r].w;
        }
    }

    if (lane == 0) { s_m[wave] = m; s_l[wave] = l; }
    *(float4*)&s_acc[wave][lane * 4] = make_float4(ax, ay, az, aw);
    __syncthreads();

    // ---- cross-wave merge (redundant scalar math on all threads: cheap) ----
    const float M = fmaxf(fmaxf(s_m[0], s_m[1]), fmaxf(s_m[2], s_m[3]));
    const float sc0 = __expf(s_m[0] - M), sc1 = __expf(s_m[1] - M);
    const float sc2 = __expf(s_m[2] - M), sc3 = __expf(s_m[3] - M);
    const float L = s_l[0] * sc0 + s_l[1] * sc1 + s_l[2] * sc2 + s_l[3] * sc3;
    const float invL = 1.0f / L;

    const float o = (s_acc[0][t] * sc0 + s_acc[1][t] * sc1 +
                     s_acc[2][t] * sc2 + s_acc[3][t] * sc3) * invL;
    out_att[(size_t)b * KD + t] = o;

    // exp(-inf - M) == 0 handles masked entries exactly
    out_alpha[(size_t)b * NK + t]       = __expf(s_alpha[t]       - M) * invL;
    out_alpha[(size_t)b * NK + t + 256] = __expf(s_alpha[t + 256] - M) * invL;
}

extern "C" void kernel_launch(void* const* d_in, const int* in_sizes, int n_in,
                              void* d_out, int out_size, void* d_ws, size_t ws_size,
                              hipStream_t stream) {
    const float* queries = (const float*)d_in[0];   // (2048, 512)
    const float* keys    = (const float*)d_in[1];   // (2048, 512, 256)
    // d_in[2] = trans_keys — unused by the reference
    const void*  mask    = d_in[3];                 // (2048, 512) bool (dtype probed per block)
    const float* W       = (const float*)d_in[4];   // (256, 512)
    const float* bias    = (const float*)d_in[5];   // (256,)

    float* out_att   = (float*)d_out;                         // (2048, 256)
    float* out_alpha = (float*)d_out + (size_t)NBATCH * KD;   // (2048, 512)
    float* TQ        = (float*)d_ws;                          // (2048, 256) scratch

    tq_gemm<<<NBATCH / 4, 256, 0, stream>>>(queries, W, bias, TQ);
    attn_fused<<<NBATCH, 256, 0, stream>>>(keys, mask, TQ, out_att, out_alpha);
}

// Round 4
// 236.923 us; speedup vs baseline: 1.0417x; 1.0417x over previous
//
#include <hip/hip_runtime.h>
#include <stdint.h>

#define QD 512   // query_dim
#define KD 256   // key_dim
#define NBATCH 2048
#define NK 512   // n_keys

// ---------------------------------------------------------------------------
// Kernel 1: TQ[b][k] = sum_q Q[b][q] * W[k][q] + bias[k]      (B=2048, KD=256)
// ---------------------------------------------------------------------------
__global__ __launch_bounds__(256) void tq_gemm(const float* __restrict__ Q,
                                               const float* __restrict__ W,
                                               const float* __restrict__ bias,
                                               float* __restrict__ TQ) {
    __shared__ float qs[4][QD];
    const int b0 = blockIdx.x * 4;

    const float4* Qv = (const float4*)(Q + (size_t)b0 * QD);
    float4* qsv = (float4*)&qs[0][0];
    qsv[threadIdx.x]       = Qv[threadIdx.x];
    qsv[threadIdx.x + 256] = Qv[threadIdx.x + 256];
    __syncthreads();

    const int k = threadIdx.x;
    const float4* Wv = (const float4*)(W + (size_t)k * QD);

    float a0 = 0.f, a1 = 0.f, a2 = 0.f, a3 = 0.f;
#pragma unroll 4
    for (int kk = 0; kk < QD / 4; ++kk) {
        float4 w4 = Wv[kk];
        float4 q0 = *(const float4*)&qs[0][kk * 4];
        float4 q1 = *(const float4*)&qs[1][kk * 4];
        float4 q2 = *(const float4*)&qs[2][kk * 4];
        float4 q3 = *(const float4*)&qs[3][kk * 4];
        a0 += w4.x * q0.x + w4.y * q0.y + w4.z * q0.z + w4.w * q0.w;
        a1 += w4.x * q1.x + w4.y * q1.y + w4.z * q1.z + w4.w * q1.w;
        a2 += w4.x * q2.x + w4.y * q2.y + w4.z * q2.z + w4.w * q2.w;
        a3 += w4.x * q3.x + w4.y * q3.y + w4.z * q3.z + w4.w * q3.w;
    }
    const float bb = bias[k];
    TQ[(size_t)(b0 + 0) * KD + k] = a0 + bb;
    TQ[(size_t)(b0 + 1) * KD + k] = a1 + bb;
    TQ[(size_t)(b0 + 2) * KD + k] = a2 + bb;
    TQ[(size_t)(b0 + 3) * KD + k] = a3 + bb;
}

// ---------------------------------------------------------------------------
// Kernel 2: fused  alpha = keys . tq -> mask -> online softmax -> PV
// One block (4 waves) per batch; wave owns 128 rows. Wave is split into
// 4 x 16-lane groups; group g handles row 4i+g, lane owns 16 columns
// (4 float4 at col j*64 + sub*4). Loads remain fully coalesced (64x16B).
// Per 4 rows: 4-level xor-reduce within 16 lanes + 2 shfl for group max
// (1.5 DS ops/row vs 6) and ONE exp (vs 4). 2-stage load pipeline keeps
// ~8KB/wave in flight. keys read EXACTLY ONCE (1.074 GB).
// ---------------------------------------------------------------------------
__global__ __launch_bounds__(256) void attn_fused(const float* __restrict__ keys,
                                                  const void* __restrict__ maskp,
                                                  const float* __restrict__ TQ,
                                                  float* __restrict__ out_att,
                                                  float* __restrict__ out_alpha) {
    const int b    = blockIdx.x;
    const int t    = threadIdx.x;
    const int wave = t >> 6;
    const int lane = t & 63;
    const int grp  = lane >> 4;      // 0..3  (row within 4-row pack)
    const int sub  = lane & 15;      // 0..15 (column slice)

    __shared__ float s_bias[NK];     // 0 or -inf
    __shared__ float s_alpha[NK];    // raw (masked) logits
    __shared__ float s_acc[4][KD];   // per-wave PV partials
    __shared__ float s_m[4], s_l[4];
    __shared__ int   s_flag[4];

    // ---- Phase 0: mask dtype probe (from buffer HEAD: valid both dtypes) ----
    const uint32_t* mg = (const uint32_t*)maskp;
    const uint32_t pv = (t < 128) ? mg[t] : 0u;       // first 512 bytes
    const unsigned long long bal = __ballot(pv > 1u);
    if (lane == 0) s_flag[wave] = (bal != 0ull);
    __syncthreads();
    const int bytemask = s_flag[0] | s_flag[1] | s_flag[2] | s_flag[3];

    if (bytemask) {
        const uint32_t* mb8 = (const uint32_t*)((const uint8_t*)maskp + (size_t)b * NK);
        if (t < NK / 4) {                             // 512 bytes = 128 words
            const uint32_t w = mb8[t];
            s_bias[4 * t + 0] = (w & 0x000000FFu) ? -INFINITY : 0.f;
            s_bias[4 * t + 1] = (w & 0x0000FF00u) ? -INFINITY : 0.f;
            s_bias[4 * t + 2] = (w & 0x00FF0000u) ? -INFINITY : 0.f;
            s_bias[4 * t + 3] = (w & 0xFF000000u) ? -INFINITY : 0.f;
        }
    } else {
        const uint2 wv = ((const uint2*)((const uint32_t*)maskp + (size_t)b * NK))[t];
        s_bias[2 * t + 0] = wv.x ? -INFINITY : 0.f;
        s_bias[2 * t + 1] = wv.y ? -INFINITY : 0.f;
    }
    __syncthreads();

    // ---- TQ fragments: lane's 16 columns, 4-way replicated across groups ----
    const float* tqb = TQ + (size_t)b * KD + sub * 4;
    const float4 tq0 = *(const float4*)(tqb +   0);
    const float4 tq1 = *(const float4*)(tqb +  64);
    const float4 tq2 = *(const float4*)(tqb + 128);
    const float4 tq3 = *(const float4*)(tqb + 192);

    const int n0 = wave * (NK / 4);
    const float* p = keys + (size_t)b * NK * KD + (size_t)(n0 + grp) * KD + sub * 4;

    float m = -1e30f, l = 0.f;
    float4 a0 = {0,0,0,0}, a1 = {0,0,0,0}, a2 = {0,0,0,0}, a3 = {0,0,0,0};

#define LOADG(i, K0, K1, K2, K3) do {                                   \
    const float* q_ = p + (size_t)(i) * 4 * KD;                         \
    K0 = *(const float4*)(q_ +   0);                                    \
    K1 = *(const float4*)(q_ +  64);                                    \
    K2 = *(const float4*)(q_ + 128);                                    \
    K3 = *(const float4*)(q_ + 192);                                    \
} while (0)

#define COMPUTE(i, K0, K1, K2, K3) do {                                 \
    float d_ = K0.x*tq0.x + K0.y*tq0.y + K0.z*tq0.z + K0.w*tq0.w;       \
    d_ += K1.x*tq1.x + K1.y*tq1.y + K1.z*tq1.z + K1.w*tq1.w;            \
    d_ += K2.x*tq2.x + K2.y*tq2.y + K2.z*tq2.z + K2.w*tq2.w;            \
    d_ += K3.x*tq3.x + K3.y*tq3.y + K3.z*tq3.z + K3.w*tq3.w;            \
    d_ += __shfl_xor(d_, 8, 64);                                        \
    d_ += __shfl_xor(d_, 4, 64);                                        \
    d_ += __shfl_xor(d_, 2, 64);                                        \
    d_ += __shfl_xor(d_, 1, 64);                                        \
    const int n_ = n0 + 4 * (i) + grp;                                  \
    const float aval_ = d_ + s_bias[n_];                                \
    if (sub == 0) s_alpha[n_] = aval_;                                  \
    float mx_ = fmaxf(aval_, __shfl_xor(aval_, 16, 64));                \
    mx_ = fmaxf(mx_, __shfl_xor(mx_, 32, 64));                          \
    if (mx_ > m) {  /* wave-uniform -> s_branch, rare (~6x/wave) */     \
        const float sc_ = __expf(m - mx_);                              \
        l *= sc_;                                                       \
        a0.x *= sc_; a0.y *= sc_; a0.z *= sc_; a0.w *= sc_;             \
        a1.x *= sc_; a1.y *= sc_; a1.z *= sc_; a1.w *= sc_;             \
        a2.x *= sc_; a2.y *= sc_; a2.z *= sc_; a2.w *= sc_;             \
        a3.x *= sc_; a3.y *= sc_; a3.z *= sc_; a3.w *= sc_;             \
        m = mx_;                                                        \
    }                                                                   \
    const float w_ = __expf(aval_ - m);  /* per-lane: its group's row */ \
    l += w_;                                                            \
    a0.x += w_*K0.x; a0.y += w_*K0.y; a0.z += w_*K0.z; a0.w += w_*K0.w; \
    a1.x += w_*K1.x; a1.y += w_*K1.y; a1.z += w_*K1.z; a1.w += w_*K1.w; \
    a2.x += w_*K2.x; a2.y += w_*K2.y; a2.z += w_*K2.z; a2.w += w_*K2.w; \
    a3.x += w_*K3.x; a3.y += w_*K3.y; a3.z += w_*K3.z; a3.w += w_*K3.w; \
} while (0)

    // ---- Main loop: 32 group-iters of 4 rows, 2-stage pipeline ----
    float4 A0, A1, A2, A3, B0, B1, B2, B3;
    LOADG(0, A0, A1, A2, A3);
    for (int i = 0; i < 32; i += 2) {
        LOADG(i + 1, B0, B1, B2, B3);
        COMPUTE(i, A0, A1, A2, A3);
        if (i + 2 < 32) LOADG(i + 2, A0, A1, A2, A3);
        COMPUTE(i + 1, B0, B1, B2, B3);
    }

    // ---- cross-group reduce (bits 4,5), once per wave ----
#define RED2(x) do { x += __shfl_xor(x, 16, 64); x += __shfl_xor(x, 32, 64); } while (0)
    RED2(l);
    RED2(a0.x); RED2(a0.y); RED2(a0.z); RED2(a0.w);
    RED2(a1.x); RED2(a1.y); RED2(a1.z); RED2(a1.w);
    RED2(a2.x); RED2(a2.y); RED2(a2.z); RED2(a2.w);
    RED2(a3.x); RED2(a3.y); RED2(a3.z); RED2(a3.w);

    if (lane == 0) { s_m[wave] = m; s_l[wave] = l; }
    float4 av;
    av.x = grp == 0 ? a0.x : grp == 1 ? a1.x : grp == 2 ? a2.x : a3.x;
    av.y = grp == 0 ? a0.y : grp == 1 ? a1.y : grp == 2 ? a2.y : a3.y;
    av.z = grp == 0 ? a0.z : grp == 1 ? a1.z : grp == 2 ? a2.z : a3.z;
    av.w = grp == 0 ? a0.w : grp == 1 ? a1.w : grp == 2 ? a2.w : a3.w;
    *(float4*)&s_acc[wave][grp * 64 + sub * 4] = av;
    __syncthreads();

    // ---- cross-wave merge (redundant scalar math on all threads) ----
    const float M = fmaxf(fmaxf(s_m[0], s_m[1]), fmaxf(s_m[2], s_m[3]));
    const float sc0 = __expf(s_m[0] - M), sc1 = __expf(s_m[1] - M);
    const float sc2 = __expf(s_m[2] - M), sc3 = __expf(s_m[3] - M);
    const float L = s_l[0] * sc0 + s_l[1] * sc1 + s_l[2] * sc2 + s_l[3] * sc3;
    const float invL = 1.0f / L;

    const float o = (s_acc[0][t] * sc0 + s_acc[1][t] * sc1 +
                     s_acc[2][t] * sc2 + s_acc[3][t] * sc3) * invL;
    out_att[(size_t)b * KD + t] = o;

    // exp(-inf - M) == 0 handles masked entries exactly
    out_alpha[(size_t)b * NK + t]       = __expf(s_alpha[t]       - M) * invL;
    out_alpha[(size_t)b * NK + t + 256] = __expf(s_alpha[t + 256] - M) * invL;
}

extern "C" void kernel_launch(void* const* d_in, const int* in_sizes, int n_in,
                              void* d_out, int out_size, void* d_ws, size_t ws_size,
                              hipStream_t stream) {
    const float* queries = (const float*)d_in[0];   // (2048, 512)
    const float* keys    = (const float*)d_in[1];   // (2048, 512, 256)
    // d_in[2] = trans_keys — unused by the reference
    const void*  mask    = d_in[3];                 // (2048, 512) bool (dtype probed)
    const float* W       = (const float*)d_in[4];   // (256, 512)
    const float* bias    = (const float*)d_in[5];   // (256,)

    float* out_att   = (float*)d_out;                         // (2048, 256)
    float* out_alpha = (float*)d_out + (size_t)NBATCH * KD;   // (2048, 512)
    float* TQ        = (float*)d_ws;                          // (2048, 256) scratch

    tq_gemm<<<NBATCH / 4, 256, 0, stream>>>(queries, W, bias, TQ);
    attn_fused<<<NBATCH, 256, 0, stream>>>(keys, mask, TQ, out_att, out_alpha);
}

// Round 6
// 214.931 us; speedup vs baseline: 1.1482x; 1.1023x over previous
//
#include <hip/hip_runtime.h>
#include <stdint.h>

#define QD 512   // query_dim
#define KD 256   // key_dim
#define NBATCH 2048
#define NK 512   // n_keys

// native clang vector type — __builtin_nontemporal_* rejects HIP_vector_type
typedef float nfloat4 __attribute__((ext_vector_type(4)));

// non-temporal float4 load: stream keys past the caches without polluting.
__device__ __forceinline__ float4 ldnt4(const float* p) {
    nfloat4 v = __builtin_nontemporal_load((const nfloat4*)p);
    return make_float4(v.x, v.y, v.z, v.w);
}
__device__ __forceinline__ void stnt(float* p, float v) {
    __builtin_nontemporal_store(v, p);
}

// ---------------------------------------------------------------------------
// Kernel 1: TQ[b][k] = sum_q Q[b][q] * W[k][q] + bias[k]      (B=2048, KD=256)
// ---------------------------------------------------------------------------
__global__ __launch_bounds__(256) void tq_gemm(const float* __restrict__ Q,
                                               const float* __restrict__ W,
                                               const float* __restrict__ bias,
                                               float* __restrict__ TQ) {
    __shared__ float qs[4][QD];
    const int b0 = blockIdx.x * 4;

    const float4* Qv = (const float4*)(Q + (size_t)b0 * QD);
    float4* qsv = (float4*)&qs[0][0];
    qsv[threadIdx.x]       = Qv[threadIdx.x];
    qsv[threadIdx.x + 256] = Qv[threadIdx.x + 256];
    __syncthreads();

    const int k = threadIdx.x;
    const float4* Wv = (const float4*)(W + (size_t)k * QD);

    float a0 = 0.f, a1 = 0.f, a2 = 0.f, a3 = 0.f;
#pragma unroll 4
    for (int kk = 0; kk < QD / 4; ++kk) {
        float4 w4 = Wv[kk];
        float4 q0 = *(const float4*)&qs[0][kk * 4];
        float4 q1 = *(const float4*)&qs[1][kk * 4];
        float4 q2 = *(const float4*)&qs[2][kk * 4];
        float4 q3 = *(const float4*)&qs[3][kk * 4];
        a0 += w4.x * q0.x + w4.y * q0.y + w4.z * q0.z + w4.w * q0.w;
        a1 += w4.x * q1.x + w4.y * q1.y + w4.z * q1.z + w4.w * q1.w;
        a2 += w4.x * q2.x + w4.y * q2.y + w4.z * q2.z + w4.w * q2.w;
        a3 += w4.x * q3.x + w4.y * q3.y + w4.z * q3.z + w4.w * q3.w;
    }
    const float bb = bias[k];
    TQ[(size_t)(b0 + 0) * KD + k] = a0 + bb;
    TQ[(size_t)(b0 + 1) * KD + k] = a1 + bb;
    TQ[(size_t)(b0 + 2) * KD + k] = a2 + bb;
    TQ[(size_t)(b0 + 3) * KD + k] = a3 + bb;
}

// ---------------------------------------------------------------------------
// Kernel 2: fused  alpha = keys . tq -> mask -> online softmax -> PV
// Identical structure to R4 (4 x 16-lane groups, 2-stage pipeline); the ONLY
// change: key loads are NON-TEMPORAL (keys are one-touch; avoid cache
// allocate+evict churn on the 1 GiB stream), outputs NT-stored.
// ---------------------------------------------------------------------------
__global__ __launch_bounds__(256) void attn_fused(const float* __restrict__ keys,
                                                  const void* __restrict__ maskp,
                                                  const float* __restrict__ TQ,
                                                  float* __restrict__ out_att,
                                                  float* __restrict__ out_alpha) {
    const int b    = blockIdx.x;
    const int t    = threadIdx.x;
    const int wave = t >> 6;
    const int lane = t & 63;
    const int grp  = lane >> 4;      // 0..3  (row within 4-row pack)
    const int sub  = lane & 15;      // 0..15 (column slice)

    __shared__ float s_bias[NK];     // 0 or -inf
    __shared__ float s_alpha[NK];    // raw (masked) logits
    __shared__ float s_acc[4][KD];   // per-wave PV partials
    __shared__ float s_m[4], s_l[4];
    __shared__ int   s_flag[4];

    // ---- Phase 0: mask dtype probe (from buffer HEAD: valid both dtypes) ----
    const uint32_t* mg = (const uint32_t*)maskp;
    const uint32_t pv = (t < 128) ? mg[t] : 0u;       // first 512 bytes
    const unsigned long long bal = __ballot(pv > 1u);
    if (lane == 0) s_flag[wave] = (bal != 0ull);
    __syncthreads();
    const int bytemask = s_flag[0] | s_flag[1] | s_flag[2] | s_flag[3];

    if (bytemask) {
        const uint32_t* mb8 = (const uint32_t*)((const uint8_t*)maskp + (size_t)b * NK);
        if (t < NK / 4) {                             // 512 bytes = 128 words
            const uint32_t w = mb8[t];
            s_bias[4 * t + 0] = (w & 0x000000FFu) ? -INFINITY : 0.f;
            s_bias[4 * t + 1] = (w & 0x0000FF00u) ? -INFINITY : 0.f;
            s_bias[4 * t + 2] = (w & 0x00FF0000u) ? -INFINITY : 0.f;
            s_bias[4 * t + 3] = (w & 0xFF000000u) ? -INFINITY : 0.f;
        }
    } else {
        const uint2 wv = ((const uint2*)((const uint32_t*)maskp + (size_t)b * NK))[t];
        s_bias[2 * t + 0] = wv.x ? -INFINITY : 0.f;
        s_bias[2 * t + 1] = wv.y ? -INFINITY : 0.f;
    }
    __syncthreads();

    // ---- TQ fragments: lane's 16 columns, 4-way replicated across groups ----
    const float* tqb = TQ + (size_t)b * KD + sub * 4;
    const float4 tq0 = *(const float4*)(tqb +   0);
    const float4 tq1 = *(const float4*)(tqb +  64);
    const float4 tq2 = *(const float4*)(tqb + 128);
    const float4 tq3 = *(const float4*)(tqb + 192);

    const int n0 = wave * (NK / 4);
    const float* p = keys + (size_t)b * NK * KD + (size_t)(n0 + grp) * KD + sub * 4;

    float m = -1e30f, l = 0.f;
    float4 a0 = {0,0,0,0}, a1 = {0,0,0,0}, a2 = {0,0,0,0}, a3 = {0,0,0,0};

#define LOADG(i, K0, K1, K2, K3) do {                                   \
    const float* q_ = p + (size_t)(i) * 4 * KD;                         \
    K0 = ldnt4(q_ +   0);                                               \
    K1 = ldnt4(q_ +  64);                                               \
    K2 = ldnt4(q_ + 128);                                               \
    K3 = ldnt4(q_ + 192);                                               \
} while (0)

#define COMPUTE(i, K0, K1, K2, K3) do {                                 \
    float d_ = K0.x*tq0.x + K0.y*tq0.y + K0.z*tq0.z + K0.w*tq0.w;       \
    d_ += K1.x*tq1.x + K1.y*tq1.y + K1.z*tq1.z + K1.w*tq1.w;            \
    d_ += K2.x*tq2.x + K2.y*tq2.y + K2.z*tq2.z + K2.w*tq2.w;            \
    d_ += K3.x*tq3.x + K3.y*tq3.y + K3.z*tq3.z + K3.w*tq3.w;            \
    d_ += __shfl_xor(d_, 8, 64);                                        \
    d_ += __shfl_xor(d_, 4, 64);                                        \
    d_ += __shfl_xor(d_, 2, 64);                                        \
    d_ += __shfl_xor(d_, 1, 64);                                        \
    const int n_ = n0 + 4 * (i) + grp;                                  \
    const float aval_ = d_ + s_bias[n_];                                \
    if (sub == 0) s_alpha[n_] = aval_;                                  \
    float mx_ = fmaxf(aval_, __shfl_xor(aval_, 16, 64));                \
    mx_ = fmaxf(mx_, __shfl_xor(mx_, 32, 64));                          \
    if (mx_ > m) {  /* wave-uniform -> s_branch, rare (~6x/wave) */     \
        const float sc_ = __expf(m - mx_);                              \
        l *= sc_;                                                       \
        a0.x *= sc_; a0.y *= sc_; a0.z *= sc_; a0.w *= sc_;             \
        a1.x *= sc_; a1.y *= sc_; a1.z *= sc_; a1.w *= sc_;             \
        a2.x *= sc_; a2.y *= sc_; a2.z *= sc_; a2.w *= sc_;             \
        a3.x *= sc_; a3.y *= sc_; a3.z *= sc_; a3.w *= sc_;             \
        m = mx_;                                                        \
    }                                                                   \
    const float w_ = __expf(aval_ - m);  /* per-lane: its group's row */ \
    l += w_;                                                            \
    a0.x += w_*K0.x; a0.y += w_*K0.y; a0.z += w_*K0.z; a0.w += w_*K0.w; \
    a1.x += w_*K1.x; a1.y += w_*K1.y; a1.z += w_*K1.z; a1.w += w_*K1.w; \
    a2.x += w_*K2.x; a2.y += w_*K2.y; a2.z += w_*K2.z; a2.w += w_*K2.w; \
    a3.x += w_*K3.x; a3.y += w_*K3.y; a3.z += w_*K3.z; a3.w += w_*K3.w; \
} while (0)

    // ---- Main loop: 32 group-iters of 4 rows, 2-stage pipeline ----
    float4 A0, A1, A2, A3, B0, B1, B2, B3;
    LOADG(0, A0, A1, A2, A3);
    for (int i = 0; i < 32; i += 2) {
        LOADG(i + 1, B0, B1, B2, B3);
        COMPUTE(i, A0, A1, A2, A3);
        if (i + 2 < 32) LOADG(i + 2, A0, A1, A2, A3);
        COMPUTE(i + 1, B0, B1, B2, B3);
    }

    // ---- cross-group reduce (bits 4,5), once per wave ----
#define RED2(x) do { x += __shfl_xor(x, 16, 64); x += __shfl_xor(x, 32, 64); } while (0)
    RED2(l);
    RED2(a0.x); RED2(a0.y); RED2(a0.z); RED2(a0.w);
    RED2(a1.x); RED2(a1.y); RED2(a1.z); RED2(a1.w);
    RED2(a2.x); RED2(a2.y); RED2(a2.z); RED2(a2.w);
    RED2(a3.x); RED2(a3.y); RED2(a3.z); RED2(a3.w);

    if (lane == 0) { s_m[wave] = m; s_l[wave] = l; }
    float4 av;
    av.x = grp == 0 ? a0.x : grp == 1 ? a1.x : grp == 2 ? a2.x : a3.x;
    av.y = grp == 0 ? a0.y : grp == 1 ? a1.y : grp == 2 ? a2.y : a3.y;
    av.z = grp == 0 ? a0.z : grp == 1 ? a1.z : grp == 2 ? a2.z : a3.z;
    av.w = grp == 0 ? a0.w : grp == 1 ? a1.w : grp == 2 ? a2.w : a3.w;
    *(float4*)&s_acc[wave][grp * 64 + sub * 4] = av;
    __syncthreads();

    // ---- cross-wave merge (redundant scalar math on all threads) ----
    const float M = fmaxf(fmaxf(s_m[0], s_m[1]), fmaxf(s_m[2], s_m[3]));
    const float sc0 = __expf(s_m[0] - M), sc1 = __expf(s_m[1] - M);
    const float sc2 = __expf(s_m[2] - M), sc3 = __expf(s_m[3] - M);
    const float L = s_l[0] * sc0 + s_l[1] * sc1 + s_l[2] * sc2 + s_l[3] * sc3;
    const float invL = 1.0f / L;

    const float o = (s_acc[0][t] * sc0 + s_acc[1][t] * sc1 +
                     s_acc[2][t] * sc2 + s_acc[3][t] * sc3) * invL;
    stnt(out_att + (size_t)b * KD + t, o);

    // exp(-inf - M) == 0 handles masked entries exactly
    stnt(out_alpha + (size_t)b * NK + t,       __expf(s_alpha[t]       - M) * invL);
    stnt(out_alpha + (size_t)b * NK + t + 256, __expf(s_alpha[t + 256] - M) * invL);
}

extern "C" void kernel_launch(void* const* d_in, const int* in_sizes, int n_in,
                              void* d_out, int out_size, void* d_ws, size_t ws_size,
                              hipStream_t stream) {
    const float* queries = (const float*)d_in[0];   // (2048, 512)
    const float* keys    = (const float*)d_in[1];   // (2048, 512, 256)
    // d_in[2] = trans_keys — unused by the reference
    const void*  mask    = d_in[3];                 // (2048, 512) bool (dtype probed)
    const float* W       = (const float*)d_in[4];   // (256, 512)
    const float* bias    = (const float*)d_in[5];   // (256,)

    float* out_att   = (float*)d_out;                         // (2048, 256)
    float* out_alpha = (float*)d_out + (size_t)NBATCH * KD;   // (2048, 512)
    float* TQ        = (float*)d_ws;                          // (2048, 256) scratch

    tq_gemm<<<NBATCH / 4, 256, 0, stream>>>(queries, W, bias, TQ);
    attn_fused<<<NBATCH, 256, 0, stream>>>(keys, mask, TQ, out_att, out_alpha);
}

// Round 7
// 204.283 us; speedup vs baseline: 1.2081x; 1.0521x over previous
//
#include <hip/hip_runtime.h>
#include <stdint.h>

#define QD 512   // query_dim
#define KD 256   // key_dim
#define NBATCH 2048
#define NK 512   // n_keys

// native clang vector type — __builtin_nontemporal_* rejects HIP_vector_type
typedef float nfloat4 __attribute__((ext_vector_type(4)));

// non-temporal float4 load: stream keys past the caches without polluting.
__device__ __forceinline__ float4 ldnt4(const float* p) {
    nfloat4 v = __builtin_nontemporal_load((const nfloat4*)p);
    return make_float4(v.x, v.y, v.z, v.w);
}
__device__ __forceinline__ void stnt(float* p, float v) {
    __builtin_nontemporal_store(v, p);
}

// ---------------------------------------------------------------------------
// Kernel 1: TQ[b][k] = sum_q Q[b][q] * W[k][q] + bias[k]      (B=2048, KD=256)
// ---------------------------------------------------------------------------
__global__ __launch_bounds__(256) void tq_gemm(const float* __restrict__ Q,
                                               const float* __restrict__ W,
                                               const float* __restrict__ bias,
                                               float* __restrict__ TQ) {
    __shared__ float qs[4][QD];
    const int b0 = blockIdx.x * 4;

    const float4* Qv = (const float4*)(Q + (size_t)b0 * QD);
    float4* qsv = (float4*)&qs[0][0];
    qsv[threadIdx.x]       = Qv[threadIdx.x];
    qsv[threadIdx.x + 256] = Qv[threadIdx.x + 256];
    __syncthreads();

    const int k = threadIdx.x;
    const float4* Wv = (const float4*)(W + (size_t)k * QD);

    float a0 = 0.f, a1 = 0.f, a2 = 0.f, a3 = 0.f;
#pragma unroll 4
    for (int kk = 0; kk < QD / 4; ++kk) {
        float4 w4 = Wv[kk];
        float4 q0 = *(const float4*)&qs[0][kk * 4];
        float4 q1 = *(const float4*)&qs[1][kk * 4];
        float4 q2 = *(const float4*)&qs[2][kk * 4];
        float4 q3 = *(const float4*)&qs[3][kk * 4];
        a0 += w4.x * q0.x + w4.y * q0.y + w4.z * q0.z + w4.w * q0.w;
        a1 += w4.x * q1.x + w4.y * q1.y + w4.z * q1.z + w4.w * q1.w;
        a2 += w4.x * q2.x + w4.y * q2.y + w4.z * q2.z + w4.w * q2.w;
        a3 += w4.x * q3.x + w4.y * q3.y + w4.z * q3.z + w4.w * q3.w;
    }
    const float bb = bias[k];
    TQ[(size_t)(b0 + 0) * KD + k] = a0 + bb;
    TQ[(size_t)(b0 + 1) * KD + k] = a1 + bb;
    TQ[(size_t)(b0 + 2) * KD + k] = a2 + bb;
    TQ[(size_t)(b0 + 3) * KD + k] = a3 + bb;
}

// ---------------------------------------------------------------------------
// Kernel 2: fused  alpha = keys . tq -> mask -> online softmax -> PV
// Same as R6 except ROW DEALING: rows are handed to waves round-robin in
// 4-row packs (row = 16*iter + 4*wave + grp), so the block's 4 waves march
// through the batch's 512 KB key slab CONTIGUOUSLY (16 KB per iteration
// round) -> 2048 long DRAM streams instead of 8192 short ones.
// ---------------------------------------------------------------------------
__global__ __launch_bounds__(256) void attn_fused(const float* __restrict__ keys,
                                                  const void* __restrict__ maskp,
                                                  const float* __restrict__ TQ,
                                                  float* __restrict__ out_att,
                                                  float* __restrict__ out_alpha) {
    const int b    = blockIdx.x;
    const int t    = threadIdx.x;
    const int wave = t >> 6;
    const int lane = t & 63;
    const int grp  = lane >> 4;      // 0..3  (row within 4-row pack)
    const int sub  = lane & 15;      // 0..15 (column slice)

    __shared__ float s_bias[NK];     // 0 or -inf
    __shared__ float s_alpha[NK];    // raw (masked) logits
    __shared__ float s_acc[4][KD];   // per-wave PV partials
    __shared__ float s_m[4], s_l[4];
    __shared__ int   s_flag[4];

    // ---- Phase 0: mask dtype probe (from buffer HEAD: valid both dtypes) ----
    const uint32_t* mg = (const uint32_t*)maskp;
    const uint32_t pv = (t < 128) ? mg[t] : 0u;       // first 512 bytes
    const unsigned long long bal = __ballot(pv > 1u);
    if (lane == 0) s_flag[wave] = (bal != 0ull);
    __syncthreads();
    const int bytemask = s_flag[0] | s_flag[1] | s_flag[2] | s_flag[3];

    if (bytemask) {
        const uint32_t* mb8 = (const uint32_t*)((const uint8_t*)maskp + (size_t)b * NK);
        if (t < NK / 4) {                             // 512 bytes = 128 words
            const uint32_t w = mb8[t];
            s_bias[4 * t + 0] = (w & 0x000000FFu) ? -INFINITY : 0.f;
            s_bias[4 * t + 1] = (w & 0x0000FF00u) ? -INFINITY : 0.f;
            s_bias[4 * t + 2] = (w & 0x00FF0000u) ? -INFINITY : 0.f;
            s_bias[4 * t + 3] = (w & 0xFF000000u) ? -INFINITY : 0.f;
        }
    } else {
        const uint2 wv = ((const uint2*)((const uint32_t*)maskp + (size_t)b * NK))[t];
        s_bias[2 * t + 0] = wv.x ? -INFINITY : 0.f;
        s_bias[2 * t + 1] = wv.y ? -INFINITY : 0.f;
    }
    __syncthreads();

    // ---- TQ fragments: lane's 16 columns, 4-way replicated across groups ----
    const float* tqb = TQ + (size_t)b * KD + sub * 4;
    const float4 tq0 = *(const float4*)(tqb +   0);
    const float4 tq1 = *(const float4*)(tqb +  64);
    const float4 tq2 = *(const float4*)(tqb + 128);
    const float4 tq3 = *(const float4*)(tqb + 192);

    // row for (wave, iter i, grp) = 16*i + 4*wave + grp  (block-contiguous)
    const int r0 = 4 * wave + grp;
    const float* p = keys + (size_t)b * NK * KD + (size_t)r0 * KD + sub * 4;

    float m = -1e30f, l = 0.f;
    float4 a0 = {0,0,0,0}, a1 = {0,0,0,0}, a2 = {0,0,0,0}, a3 = {0,0,0,0};

#define LOADG(i, K0, K1, K2, K3) do {                                   \
    const float* q_ = p + (size_t)(i) * 16 * KD;                        \
    K0 = ldnt4(q_ +   0);                                               \
    K1 = ldnt4(q_ +  64);                                               \
    K2 = ldnt4(q_ + 128);                                               \
    K3 = ldnt4(q_ + 192);                                               \
} while (0)

#define COMPUTE(i, K0, K1, K2, K3) do {                                 \
    float d_ = K0.x*tq0.x + K0.y*tq0.y + K0.z*tq0.z + K0.w*tq0.w;       \
    d_ += K1.x*tq1.x + K1.y*tq1.y + K1.z*tq1.z + K1.w*tq1.w;            \
    d_ += K2.x*tq2.x + K2.y*tq2.y + K2.z*tq2.z + K2.w*tq2.w;            \
    d_ += K3.x*tq3.x + K3.y*tq3.y + K3.z*tq3.z + K3.w*tq3.w;            \
    d_ += __shfl_xor(d_, 8, 64);                                        \
    d_ += __shfl_xor(d_, 4, 64);                                        \
    d_ += __shfl_xor(d_, 2, 64);                                        \
    d_ += __shfl_xor(d_, 1, 64);                                        \
    const int n_ = 16 * (i) + r0;                                       \
    const float aval_ = d_ + s_bias[n_];                                \
    if (sub == 0) s_alpha[n_] = aval_;                                  \
    float mx_ = fmaxf(aval_, __shfl_xor(aval_, 16, 64));                \
    mx_ = fmaxf(mx_, __shfl_xor(mx_, 32, 64));                          \
    if (mx_ > m) {  /* wave-uniform -> s_branch, rare (~6x/wave) */     \
        const float sc_ = __expf(m - mx_);                              \
        l *= sc_;                                                       \
        a0.x *= sc_; a0.y *= sc_; a0.z *= sc_; a0.w *= sc_;             \
        a1.x *= sc_; a1.y *= sc_; a1.z *= sc_; a1.w *= sc_;             \
        a2.x *= sc_; a2.y *= sc_; a2.z *= sc_; a2.w *= sc_;             \
        a3.x *= sc_; a3.y *= sc_; a3.z *= sc_; a3.w *= sc_;             \
        m = mx_;                                                        \
    }                                                                   \
    const float w_ = __expf(aval_ - m);  /* per-lane: its group's row */ \
    l += w_;                                                            \
    a0.x += w_*K0.x; a0.y += w_*K0.y; a0.z += w_*K0.z; a0.w += w_*K0.w; \
    a1.x += w_*K1.x; a1.y += w_*K1.y; a1.z += w_*K1.z; a1.w += w_*K1.w; \
    a2.x += w_*K2.x; a2.y += w_*K2.y; a2.z += w_*K2.z; a2.w += w_*K2.w; \
    a3.x += w_*K3.x; a3.y += w_*K3.y; a3.z += w_*K3.z; a3.w += w_*K3.w; \
} while (0)

    // ---- Main loop: 32 iters of 4 rows/wave, 2-stage pipeline ----
    float4 A0, A1, A2, A3, B0, B1, B2, B3;
    LOADG(0, A0, A1, A2, A3);
    for (int i = 0; i < 32; i += 2) {
        LOADG(i + 1, B0, B1, B2, B3);
        COMPUTE(i, A0, A1, A2, A3);
        if (i + 2 < 32) LOADG(i + 2, A0, A1, A2, A3);
        COMPUTE(i + 1, B0, B1, B2, B3);
    }

    // ---- cross-group reduce (bits 4,5), once per wave ----
#define RED2(x) do { x += __shfl_xor(x, 16, 64); x += __shfl_xor(x, 32, 64); } while (0)
    RED2(l);
    RED2(a0.x); RED2(a0.y); RED2(a0.z); RED2(a0.w);
    RED2(a1.x); RED2(a1.y); RED2(a1.z); RED2(a1.w);
    RED2(a2.x); RED2(a2.y); RED2(a2.z); RED2(a2.w);
    RED2(a3.x); RED2(a3.y); RED2(a3.z); RED2(a3.w);

    if (lane == 0) { s_m[wave] = m; s_l[wave] = l; }
    float4 av;
    av.x = grp == 0 ? a0.x : grp == 1 ? a1.x : grp == 2 ? a2.x : a3.x;
    av.y = grp == 0 ? a0.y : grp == 1 ? a1.y : grp == 2 ? a2.y : a3.y;
    av.z = grp == 0 ? a0.z : grp == 1 ? a1.z : grp == 2 ? a2.z : a3.z;
    av.w = grp == 0 ? a0.w : grp == 1 ? a1.w : grp == 2 ? a2.w : a3.w;
    *(float4*)&s_acc[wave][grp * 64 + sub * 4] = av;
    __syncthreads();

    // ---- cross-wave merge (redundant scalar math on all threads) ----
    const float M = fmaxf(fmaxf(s_m[0], s_m[1]), fmaxf(s_m[2], s_m[3]));
    const float sc0 = __expf(s_m[0] - M), sc1 = __expf(s_m[1] - M);
    const float sc2 = __expf(s_m[2] - M), sc3 = __expf(s_m[3] - M);
    const float L = s_l[0] * sc0 + s_l[1] * sc1 + s_l[2] * sc2 + s_l[3] * sc3;
    const float invL = 1.0f / L;

    const float o = (s_acc[0][t] * sc0 + s_acc[1][t] * sc1 +
                     s_acc[2][t] * sc2 + s_acc[3][t] * sc3) * invL;
    stnt(out_att + (size_t)b * KD + t, o);

    // exp(-inf - M) == 0 handles masked entries exactly
    stnt(out_alpha + (size_t)b * NK + t,       __expf(s_alpha[t]       - M) * invL);
    stnt(out_alpha + (size_t)b * NK + t + 256, __expf(s_alpha[t + 256] - M) * invL);
}

extern "C" void kernel_launch(void* const* d_in, const int* in_sizes, int n_in,
                              void* d_out, int out_size, void* d_ws, size_t ws_size,
                              hipStream_t stream) {
    const float* queries = (const float*)d_in[0];   // (2048, 512)
    const float* keys    = (const float*)d_in[1];   // (2048, 512, 256)
    // d_in[2] = trans_keys — unused by the reference
    const void*  mask    = d_in[3];                 // (2048, 512) bool (dtype probed)
    const float* W       = (const float*)d_in[4];   // (256, 512)
    const float* bias    = (const float*)d_in[5];   // (256,)

    float* out_att   = (float*)d_out;                         // (2048, 256)
    float* out_alpha = (float*)d_out + (size_t)NBATCH * KD;   // (2048, 512)
    float* TQ        = (float*)d_ws;                          // (2048, 256) scratch

    tq_gemm<<<NBATCH / 4, 256, 0, stream>>>(queries, W, bias, TQ);
    attn_fused<<<NBATCH, 256, 0, stream>>>(keys, mask, TQ, out_att, out_alpha);
}